// Round 17
// baseline (42.589 us; speedup 1.0000x reference)
//
#include <hip/hip_runtime.h>
#include <hip/hip_bf16.h>
#include <math.h>

#define IN_C 31
#define OUT_C 31
#define NPIX 16384
#define UW_OFF 7688
#define RW_OFF 8649
#define PART_OFF (640 * 1024)  // ws: 31 chunks (620 KB) + pad, then partials
#define CHUNK_BYTES 20480      // 20 KB of packed B-fragments per input channel i

typedef __attribute__((ext_vector_type(8))) _Float16 f16x8;
typedef __attribute__((ext_vector_type(4))) float f32x4;

__device__ inline short f2h(float f) {            // prep kernel only (cold): RNE
    union { _Float16 h; short s; } cv;
    cv.h = (_Float16)f;
    return cv.s;
}

// ---------------- prep: pack generator weights into MFMA B-fragment chunks ----
// ws layout: for i in [0,31): 20 chunks of 1 KB (20 KB per i, 620 KB total):
//   pairs 0..7 : spline B, chunk = kc*2 + nt  (kc in [0,8), nt in {0,1})
//   pair 8 (chunks 16,17) : uw B;  pair 9 (chunks 18,19) : rw B   (FP16)
__global__ __launch_bounds__(64) void kan_prep_kernel(
    const float* __restrict__ gw, const float* __restrict__ gb,
    unsigned short* __restrict__ ws)
{
    const int blk = blockIdx.x;          // 31*20 = 620
    const int i   = blk / 20;
    const int ch  = blk % 20;
    const int l   = threadIdx.x;
    const int col = l & 15;
    const int krow = l >> 4;
    const int o = (ch & 1) * 16 + col;

    int p;
    if (ch < 16)      p = (i * 31 + o) * 8 + (ch >> 1);
    else if (ch < 18) p = UW_OFF + i * 31 + o;
    else              p = RW_OFF + i * 31 + o;

    short v8[8];
#pragma unroll
    for (int j = 0; j < 8; ++j) {
        const int c = krow * 8 + j;
        float v = 0.f;
        if (o < OUT_C) v = (c < IN_C) ? gw[p * 31 + c] : gb[p];
        v8[j] = f2h(v);
    }
    *(f16x8*)&ws[(blk * 64 + l) * 8] = *(f16x8*)v8;
}

// Stage one 20 KB chunk into LDS via async DMA (512 threads: 1280 16B slots =
// 2 full passes + waves 0..3 take the tail).
__device__ __forceinline__ void stage_i(const unsigned char* wsrc,
                                        unsigned char* ldst, int t) {
#pragma unroll
    for (int k = 0; k < 2; ++k) {
        const int off = (k * 512 + t) * 16;
        __builtin_amdgcn_global_load_lds(
            (const __attribute__((address_space(1))) unsigned int*)(wsrc + off),
            (__attribute__((address_space(3))) unsigned int*)(ldst + off),
            16, 0, 0);
    }
    if (t < 256) {                       // wave-uniform (waves 0..3)
        const int off = (1024 + t) * 16;
        __builtin_amdgcn_global_load_lds(
            (const __attribute__((address_space(1))) unsigned int*)(wsrc + off),
            (__attribute__((address_space(3))) unsigned int*)(ldst + off),
            16, 0, 0);
    }
}

// ---------------- main: WEIGHT-STATIONARY, barrier-free inner loop ------------
// Block = 512 thr = 8 waves x 32 px (2 M-tiles) = 256 px. Block owns an
// i-GROUP (<=4 i's): stage all its weight chunks into LDS ONCE, ONE barrier,
// then run the i-bodies with ZERO barriers / ZERO DMA / ZERO vmcnt drains --
// weights are read-only in LDS, Y accumulates in registers across the group.
// This removes the per-i block-lockstep (barrier + vmcnt(0)) that pinned
// rounds 7-16 at ~40us: waves now free-run and TLP hides ds_read/MFMA chains.
// LDS = 4x20 KB = 80 KB -> 2 blocks/CU = 16 waves/CU. Grid = (64 ptiles, 8
// igroups) = 512 blocks. y=0 -> out, y>0 -> partials; combine sums.
__global__ __launch_bounds__(512) void kan_mfma13_kernel(
    const float* __restrict__ x,               // (31, 16384)
    const unsigned char* __restrict__ wsw,     // packed B fragments (bytes)
    float* __restrict__ parts,                 // (nsplit-1) x (31,16384)
    float* __restrict__ out,                   // (31, 16384)
    int nsplit)
{
    const int t = threadIdx.x;
    const int l = t & 63;
    const int w = t >> 6;                      // 0..7
    const int pix0 = blockIdx.x * 256;
    const int csize = (IN_C + nsplit - 1) / nsplit;
    const int ibase = blockIdx.y * csize;
    const int ni = min(csize, IN_C - ibase);   // 4 (last group: 3)

    __shared__ __align__(16) unsigned char bufs[4][CHUNK_BYTES]; // 80 KB

    const int n0 = w * 32;
    const int pr0 = pix0 + n0 + (l & 15);

    // stage the ENTIRE i-group's weights once (async DMA, in flight during
    // the x-fragment setup below)
    for (int ci = 0; ci < ni; ++ci)
        stage_i(wsw + (size_t)(ibase + ci) * CHUNK_BYTES, bufs[ci], t);

    // x~ fragments (f16, once per block), both M-tiles.
    f16x8 xv8f[2];
#pragma unroll
    for (int mt = 0; mt < 2; ++mt) {
        const int row = pr0 + mt * 16;
        const int cb = (l >> 4) * 8;
#pragma unroll
        for (int j = 0; j < 8; ++j) {
            const int c = cb + j;
            const float v = (c < IN_C) ? x[c * NPIX + row] : 1.0f;  // x~[31]=1
            xv8f[mt][j] = (_Float16)v;
        }
    }

    f32x4 Y[2][2];
#pragma unroll
    for (int mt = 0; mt < 2; ++mt)
#pragma unroll
        for (int nt = 0; nt < 2; ++nt) Y[mt][nt] = (f32x4){0.f, 0.f, 0.f, 0.f};

    __syncthreads();   // THE ONLY staging barrier: all weights resident

    // ---- i-bodies: no barriers, no DMA -- waves free-run ----
#pragma unroll 1
    for (int ci = 0; ci < ni; ++ci) {
        const int i = ibase + ci;
        const unsigned char* wb = bufs[ci];

        const float xa0 = x[i * NPIX + pr0];
        const float xa1 = x[i * NPIX + pr0 + 16];

        _Float16 basA[2][8];
        float silA[2];
#pragma unroll
        for (int s = 0; s < 2; ++s) {
            const float xv = (s == 0) ? xa0 : xa1;
            const float tb = (xv + 2.2f) * 2.5f;
            const float jf = floorf(tb);
            const float u  = tb - jf;
            const int  jj  = (int)jf;
            const float u2 = u * u, u3 = u2 * u;
            const float b0v = u3 * (1.f / 6.f);
            const float b1v = (-3.f * u3 + 3.f * u2 + 3.f * u + 1.f) * (1.f / 6.f);
            const float b2v = (3.f * u3 - 6.f * u2 + 4.f) * (1.f / 6.f);
            const float omu = 1.f - u;
            const float b3v = omu * omu * omu * (1.f / 6.f);
#pragma unroll
            for (int m = 0; m < 8; ++m) {
                const int d = jj - m;
                const float bv = (d == 0) ? b0v : (d == 1) ? b1v : (d == 2) ? b2v
                               : (d == 3) ? b3v : 0.f;
                basA[s][m] = (_Float16)bv;
            }
            silA[s] = xv / (1.f + __expf(-xv));
        }

        f32x4 SP[2][2];
#pragma unroll
        for (int mt = 0; mt < 2; ++mt)
#pragma unroll
            for (int nt = 0; nt < 2; ++nt) SP[mt][nt] = (f32x4){0.f, 0.f, 0.f, 0.f};

        // spline: 8 kc; B-fragments shared across both M-tiles
#pragma unroll
        for (int p = 0; p < 8; ++p) {
            const f16x8 b0 = *(const f16x8*)(wb + ((p * 2 + 0) * 64 + l) * 16);
            const f16x8 b1 = *(const f16x8*)(wb + ((p * 2 + 1) * 64 + l) * 16);
#pragma unroll
            for (int mt = 0; mt < 2; ++mt) {
                const f16x8 af = xv8f[mt] * basA[mt][p];   // 4 v_pk_mul_f16
                SP[mt][0] = __builtin_amdgcn_mfma_f32_16x16x32_f16(af, b0, SP[mt][0], 0, 0, 0);
                SP[mt][1] = __builtin_amdgcn_mfma_f32_16x16x32_f16(af, b1, SP[mt][1], 0, 0, 0);
            }
        }
        // uw (zero-C temp, folded immediately -> short live range)
        {
            const f16x8 u0 = *(const f16x8*)(wb + (16 * 64 + l) * 16);
            const f16x8 u1 = *(const f16x8*)(wb + (17 * 64 + l) * 16);
            const f32x4 z = (f32x4){0.f, 0.f, 0.f, 0.f};
#pragma unroll
            for (int mt = 0; mt < 2; ++mt) {
                const f32x4 uw0 = __builtin_amdgcn_mfma_f32_16x16x32_f16(xv8f[mt], u0, z, 0, 0, 0);
                const f32x4 uw1 = __builtin_amdgcn_mfma_f32_16x16x32_f16(xv8f[mt], u1, z, 0, 0, 0);
#pragma unroll
                for (int r = 0; r < 4; ++r) {
                    Y[mt][0][r] = fmaf(uw0[r], SP[mt][0][r], Y[mt][0][r]);
                    Y[mt][1][r] = fmaf(uw1[r], SP[mt][1][r], Y[mt][1][r]);
                }
            }
        }
        // rw (A = silu*x~, accumulate straight into Y)
        {
            const f16x8 r0 = *(const f16x8*)(wb + (18 * 64 + l) * 16);
            const f16x8 r1 = *(const f16x8*)(wb + (19 * 64 + l) * 16);
#pragma unroll
            for (int mt = 0; mt < 2; ++mt) {
                const f16x8 arw = xv8f[mt] * (_Float16)silA[mt];
                Y[mt][0] = __builtin_amdgcn_mfma_f32_16x16x32_f16(arw, r0, Y[mt][0], 0, 0, 0);
                Y[mt][1] = __builtin_amdgcn_mfma_f32_16x16x32_f16(arw, r1, Y[mt][1], 0, 0, 0);
            }
        }
    }

    // ---- weights dead; reuse bufs for the Y gather ----
    __syncthreads();   // all waves done reading weights
    float* yb = (float*)bufs;   // 256*33 floats = 33.8 KB << 80 KB
#pragma unroll
    for (int mt = 0; mt < 2; ++mt)
#pragma unroll
        for (int nt = 0; nt < 2; ++nt)
#pragma unroll
            for (int r = 0; r < 4; ++r) {
                const int p = n0 + mt * 16 + (l >> 4) * 4 + r;
                const int o = nt * 16 + (l & 15);
                if (o < OUT_C) yb[p * 33 + o] = Y[mt][nt][r];
            }
    __syncthreads();

    float* dst = (blockIdx.y == 0) ? out
               : (parts + (size_t)(blockIdx.y - 1) * OUT_C * NPIX);
    for (int idx = t; idx < 256 * OUT_C; idx += 512) {
        const int n = idx & 255, o = idx >> 8;
        dst[o * NPIX + pix0 + n] = yb[n * 33 + o];
    }
}

// ---------------- combine: out += sum of npart partials (vectorized) ----------
__global__ __launch_bounds__(256) void kan_combine_kernel(
    float* __restrict__ out, const float* __restrict__ parts, int npart)
{
    const int e = blockIdx.x * 256 + threadIdx.x;   // float4 index
    const int nv = (OUT_C * NPIX) / 4;
    if (e < nv) {
        f32x4 a = ((const f32x4*)out)[e];
        for (int j = 0; j < npart; ++j)
            a += ((const f32x4*)parts)[e + (size_t)j * nv];
        ((f32x4*)out)[e] = a;
    }
}

extern "C" void kernel_launch(void* const* d_in, const int* in_sizes, int n_in,
                              void* d_out, int out_size, void* d_ws, size_t ws_size,
                              hipStream_t stream) {
    const float* x  = (const float*)d_in[0];
    const float* gw = (const float*)d_in[1];
    const float* gb = (const float*)d_in[2];
    float* out = (float*)d_out;
    unsigned short* ws = (unsigned short*)d_ws;
    float* parts = (float*)((char*)d_ws + PART_OFF);

    // 8-way i-split: 7 f32 partials (14.3 MB). Deterministic fallback.
    const size_t part_bytes = (size_t)OUT_C * NPIX * 4;
    int nsplit = 8;
    if (ws_size < PART_OFF + 7 * part_bytes) nsplit = 4;
    if (ws_size < PART_OFF + 3 * part_bytes) nsplit = 2;

    hipLaunchKernelGGL(kan_prep_kernel, dim3(620), dim3(64), 0, stream, gw, gb, ws);
    hipLaunchKernelGGL(kan_mfma13_kernel, dim3(NPIX / 256, nsplit), dim3(512), 0, stream,
                       x, (const unsigned char*)d_ws, parts, out, nsplit);
    const int nv = (OUT_C * NPIX) / 4;                 // 126976
    hipLaunchKernelGGL(kan_combine_kernel, dim3((nv + 255) / 256), dim3(256), 0, stream,
                       out, parts, nsplit - 1);
}

// Round 18
// 41.989 us; speedup vs baseline: 1.0143x; 1.0143x over previous
//
#include <hip/hip_runtime.h>
#include <hip/hip_bf16.h>
#include <math.h>

#define IN_C 31
#define OUT_C 31
#define NPIX 16384
#define UW_OFF 7688
#define RW_OFF 8649
#define PART_OFF (640 * 1024)  // ws: 31 chunks (620 KB) + pad, then partials
#define CHUNK_BYTES 20480      // 20 KB of packed B-fragments per input channel i

typedef __attribute__((ext_vector_type(8))) _Float16 f16x8;
typedef __attribute__((ext_vector_type(4))) float f32x4;

__device__ inline short f2h(float f) {            // prep kernel only (cold): RNE
    union { _Float16 h; short s; } cv;
    cv.h = (_Float16)f;
    return cv.s;
}

// ---------------- prep: pack generator weights into MFMA B-fragment chunks ----
// ws layout: for i in [0,31): 20 chunks of 1 KB (20 KB per i, 620 KB total):
//   pairs 0..7 : spline B, chunk = kc*2 + nt  (kc in [0,8), nt in {0,1})
//   pair 8 (chunks 16,17) : uw B;  pair 9 (chunks 18,19) : rw B   (FP16)
__global__ __launch_bounds__(64) void kan_prep_kernel(
    const float* __restrict__ gw, const float* __restrict__ gb,
    unsigned short* __restrict__ ws)
{
    const int blk = blockIdx.x;          // 31*20 = 620
    const int i   = blk / 20;
    const int ch  = blk % 20;
    const int l   = threadIdx.x;
    const int col = l & 15;
    const int krow = l >> 4;
    const int o = (ch & 1) * 16 + col;

    int p;
    if (ch < 16)      p = (i * 31 + o) * 8 + (ch >> 1);
    else if (ch < 18) p = UW_OFF + i * 31 + o;
    else              p = RW_OFF + i * 31 + o;

    short v8[8];
#pragma unroll
    for (int j = 0; j < 8; ++j) {
        const int c = krow * 8 + j;
        float v = 0.f;
        if (o < OUT_C) v = (c < IN_C) ? gw[p * 31 + c] : gb[p];
        v8[j] = f2h(v);
    }
    *(f16x8*)&ws[(blk * 64 + l) * 8] = *(f16x8*)v8;
}

// Stage one 20 KB chunk into LDS via async DMA (512 threads: 1280 16B slots =
// 2 full passes + waves 0..3 take the tail).
__device__ __forceinline__ void stage_i(const unsigned char* wsrc,
                                        unsigned char* ldst, int t) {
#pragma unroll
    for (int k = 0; k < 2; ++k) {
        const int off = (k * 512 + t) * 16;
        __builtin_amdgcn_global_load_lds(
            (const __attribute__((address_space(1))) unsigned int*)(wsrc + off),
            (__attribute__((address_space(3))) unsigned int*)(ldst + off),
            16, 0, 0);
    }
    if (t < 256) {                       // wave-uniform (waves 0..3)
        const int off = (1024 + t) * 16;
        __builtin_amdgcn_global_load_lds(
            (const __attribute__((address_space(1))) unsigned int*)(wsrc + off),
            (__attribute__((address_space(3))) unsigned int*)(ldst + off),
            16, 0, 0);
    }
}

// R15's proven 2-stream body (16 px/wave, fp16): basis/silu for both i, then
// 10 fragment-pairs with BOTH streams' ds_reads + MFMAs interleaved
// (independent SPA/SPB chains), fold into Y. No barriers, no DMA inside.
__device__ __forceinline__ void compute2(
    int iA, const unsigned char* wbA, bool hasB, int iB, const unsigned char* wbB,
    const float* __restrict__ x, int pr0, f16x8 xv8f, f32x4 Y[2], int l)
{
    const float xa = x[iA * NPIX + pr0];
    const float xb = hasB ? x[iB * NPIX + pr0] : 0.f;

    _Float16 basA[8], basB[8];
    f16x8 arwA, arwB;
#pragma unroll
    for (int s = 0; s < 2; ++s) {
        const float xv = (s == 0) ? xa : xb;
        const float tb = (xv + 2.2f) * 2.5f;
        const float jf = floorf(tb);
        const float u  = tb - jf;
        const int  jj  = (int)jf;
        const float u2 = u * u, u3 = u2 * u;
        const float b0v = u3 * (1.f / 6.f);
        const float b1v = (-3.f * u3 + 3.f * u2 + 3.f * u + 1.f) * (1.f / 6.f);
        const float b2v = (3.f * u3 - 6.f * u2 + 4.f) * (1.f / 6.f);
        const float omu = 1.f - u;
        const float b3v = omu * omu * omu * (1.f / 6.f);
#pragma unroll
        for (int m = 0; m < 8; ++m) {
            const int d = jj - m;
            const float bv = (d == 0) ? b0v : (d == 1) ? b1v : (d == 2) ? b2v
                           : (d == 3) ? b3v : 0.f;
            if (s == 0) basA[m] = (_Float16)bv; else basB[m] = (_Float16)bv;
        }
        const float sil = xv / (1.f + __expf(-xv));
        if (s == 0) arwA = xv8f * (_Float16)sil;
        else        arwB = xv8f * (_Float16)sil;
    }

    f32x4 SPA[2], UWA[2], SPB[2], UWB[2];
#pragma unroll
    for (int nt = 0; nt < 2; ++nt) {
        SPA[nt] = (f32x4){0.f, 0.f, 0.f, 0.f};
        UWA[nt] = (f32x4){0.f, 0.f, 0.f, 0.f};
        SPB[nt] = (f32x4){0.f, 0.f, 0.f, 0.f};
        UWB[nt] = (f32x4){0.f, 0.f, 0.f, 0.f};
    }

#pragma unroll
    for (int p = 0; p < 10; ++p) {
        const f16x8 a0 = *(const f16x8*)(wbA + ((p * 2 + 0) * 64 + l) * 16);
        const f16x8 a1 = *(const f16x8*)(wbA + ((p * 2 + 1) * 64 + l) * 16);
        const f16x8 c0 = *(const f16x8*)(wbB + ((p * 2 + 0) * 64 + l) * 16);
        const f16x8 c1 = *(const f16x8*)(wbB + ((p * 2 + 1) * 64 + l) * 16);
        if (p < 8) {
            const f16x8 afA = xv8f * basA[p];          // 4 v_pk_mul_f16
            SPA[0] = __builtin_amdgcn_mfma_f32_16x16x32_f16(afA, a0, SPA[0], 0, 0, 0);
            SPA[1] = __builtin_amdgcn_mfma_f32_16x16x32_f16(afA, a1, SPA[1], 0, 0, 0);
            if (hasB) {
                const f16x8 afB = xv8f * basB[p];
                SPB[0] = __builtin_amdgcn_mfma_f32_16x16x32_f16(afB, c0, SPB[0], 0, 0, 0);
                SPB[1] = __builtin_amdgcn_mfma_f32_16x16x32_f16(afB, c1, SPB[1], 0, 0, 0);
            }
        } else if (p == 8) {
            UWA[0] = __builtin_amdgcn_mfma_f32_16x16x32_f16(xv8f, a0, UWA[0], 0, 0, 0);
            UWA[1] = __builtin_amdgcn_mfma_f32_16x16x32_f16(xv8f, a1, UWA[1], 0, 0, 0);
            if (hasB) {
                UWB[0] = __builtin_amdgcn_mfma_f32_16x16x32_f16(xv8f, c0, UWB[0], 0, 0, 0);
                UWB[1] = __builtin_amdgcn_mfma_f32_16x16x32_f16(xv8f, c1, UWB[1], 0, 0, 0);
            }
        } else {
            Y[0] = __builtin_amdgcn_mfma_f32_16x16x32_f16(arwA, a0, Y[0], 0, 0, 0);
            Y[1] = __builtin_amdgcn_mfma_f32_16x16x32_f16(arwA, a1, Y[1], 0, 0, 0);
            if (hasB) {
                Y[0] = __builtin_amdgcn_mfma_f32_16x16x32_f16(arwB, c0, Y[0], 0, 0, 0);
                Y[1] = __builtin_amdgcn_mfma_f32_16x16x32_f16(arwB, c1, Y[1], 0, 0, 0);
            }
        }
    }

#pragma unroll
    for (int nt = 0; nt < 2; ++nt)
#pragma unroll
        for (int r = 0; r < 4; ++r) {
            Y[nt][r] = fmaf(UWA[nt][r], SPA[nt][r], Y[nt][r]);
            if (hasB) Y[nt][r] = fmaf(UWB[nt][r], SPB[nt][r], Y[nt][r]);
        }
}

// ---------------- main: R15 body x 4 blocks/CU (40 KB LDS) --------------------
// Block = 512 thr = 8 waves x 16 px = 128 px. i-group of 4 in TWO passes over
// a 2x20KB LDS buffer pair: [stage i0,i1 -> bar -> 2-stream compute -> bar ->
// stage i2,i3 -> bar -> 2-stream compute]. 3 barriers/block; stage bubbles
// hidden by cross-block TLP (4 blocks/CU = 32 waves/CU nominal, 2x R15's LDS-
// capped 16). Grid = (128 ptiles, 8 igroups) = 1024 blocks. y=0 -> out,
// y>0 -> partials; combine sums.
__global__ __launch_bounds__(512) void kan_mfma14_kernel(
    const float* __restrict__ x,               // (31, 16384)
    const unsigned char* __restrict__ wsw,     // packed B fragments (bytes)
    float* __restrict__ parts,                 // (nsplit-1) x (31,16384)
    float* __restrict__ out,                   // (31, 16384)
    int nsplit)
{
    const int t = threadIdx.x;
    const int l = t & 63;
    const int w = t >> 6;                      // 0..7
    const int pix0 = blockIdx.x * 128;
    const int csize = (IN_C + nsplit - 1) / nsplit;   // 4
    const int ibase = blockIdx.y * csize;
    const int iend = min(ibase + csize, IN_C);        // ni = 4 (last group 3)

    __shared__ __align__(16) unsigned char bufs[2][CHUNK_BYTES]; // 40 KB

    const int n0 = w * 16;
    const int pr0 = pix0 + n0 + (l & 15);      // this lane's pixel row

    // pass-0 stage (async, in flight during x-fragment setup)
    stage_i(wsw + (size_t)ibase * CHUNK_BYTES, bufs[0], t);
    stage_i(wsw + (size_t)(ibase + 1) * CHUNK_BYTES, bufs[1], t);

    // x~ fragment (f16, once per block): lane holds c = (l>>4)*8 + j
    f16x8 xv8f;
    {
        const int cb = (l >> 4) * 8;
#pragma unroll
        for (int j = 0; j < 8; ++j) {
            const int c = cb + j;
            const float v = (c < IN_C) ? x[c * NPIX + pr0] : 1.0f;  // x~[31]=1
            xv8f[j] = (_Float16)v;
        }
    }

    f32x4 Y[2];
    Y[0] = (f32x4){0.f, 0.f, 0.f, 0.f};
    Y[1] = (f32x4){0.f, 0.f, 0.f, 0.f};

    __syncthreads();   // pass-0 data ready (drains vmcnt)

    // ---- pass 0: i0, i1 (both always exist: min group size is 3) ----
    compute2(ibase, bufs[0], true, ibase + 1, bufs[1], x, pr0, xv8f, Y, l);

    __syncthreads();   // all waves done reading bufs

    // ---- pass 1: i2 (always exists), i3 (last group: absent) ----
    const bool has3 = (ibase + 3) < iend;
    stage_i(wsw + (size_t)(ibase + 2) * CHUNK_BYTES, bufs[0], t);
    if (has3)
        stage_i(wsw + (size_t)(ibase + 3) * CHUNK_BYTES, bufs[1], t);

    __syncthreads();   // pass-1 data ready

    compute2(ibase + 2, bufs[0], has3, ibase + 3, bufs[1], x, pr0, xv8f, Y, l);

    // ---- gather Y into bufs (free now) for coalesced store ----
    __syncthreads();
    float* yb = (float*)bufs;   // 128*33 floats = 16.9 KB <= 40 KB
#pragma unroll
    for (int nt = 0; nt < 2; ++nt)
#pragma unroll
        for (int r = 0; r < 4; ++r) {
            const int p = n0 + (l >> 4) * 4 + r;
            const int o = nt * 16 + (l & 15);
            if (o < OUT_C) yb[p * 33 + o] = Y[nt][r];
        }
    __syncthreads();

    float* dst = (blockIdx.y == 0) ? out
               : (parts + (size_t)(blockIdx.y - 1) * OUT_C * NPIX);
    for (int idx = t; idx < 128 * OUT_C; idx += 512) {
        const int n = idx & 127, o = idx >> 7;
        dst[o * NPIX + pix0 + n] = yb[n * 33 + o];
    }
}

// ---------------- combine: out += sum of npart partials (vectorized) ----------
__global__ __launch_bounds__(256) void kan_combine_kernel(
    float* __restrict__ out, const float* __restrict__ parts, int npart)
{
    const int e = blockIdx.x * 256 + threadIdx.x;   // float4 index
    const int nv = (OUT_C * NPIX) / 4;
    if (e < nv) {
        f32x4 a = ((const f32x4*)out)[e];
        for (int j = 0; j < npart; ++j)
            a += ((const f32x4*)parts)[e + (size_t)j * nv];
        ((f32x4*)out)[e] = a;
    }
}

extern "C" void kernel_launch(void* const* d_in, const int* in_sizes, int n_in,
                              void* d_out, int out_size, void* d_ws, size_t ws_size,
                              hipStream_t stream) {
    const float* x  = (const float*)d_in[0];
    const float* gw = (const float*)d_in[1];
    const float* gb = (const float*)d_in[2];
    float* out = (float*)d_out;
    unsigned short* ws = (unsigned short*)d_ws;
    float* parts = (float*)((char*)d_ws + PART_OFF);

    // 8-way i-split: 7 f32 partials (14.3 MB). Deterministic fallback.
    const size_t part_bytes = (size_t)OUT_C * NPIX * 4;
    int nsplit = 8;
    if (ws_size < PART_OFF + 7 * part_bytes) nsplit = 4;
    if (ws_size < PART_OFF + 3 * part_bytes) nsplit = 2;

    hipLaunchKernelGGL(kan_prep_kernel, dim3(620), dim3(64), 0, stream, gw, gb, ws);
    hipLaunchKernelGGL(kan_mfma14_kernel, dim3(NPIX / 128, nsplit), dim3(512), 0, stream,
                       x, (const unsigned char*)d_ws, parts, out, nsplit);
    const int nv = (OUT_C * NPIX) / 4;                 // 126976
    hipLaunchKernelGGL(kan_combine_kernel, dim3((nv + 255) / 256), dim3(256), 0, stream,
                       out, parts, nsplit - 1);
}

// Round 19
// 41.899 us; speedup vs baseline: 1.0165x; 1.0021x over previous
//
#include <hip/hip_runtime.h>
#include <hip/hip_bf16.h>
#include <math.h>

#define IN_C 31
#define OUT_C 31
#define NPIX 16384
#define UW_OFF 7688
#define RW_OFF 8649
#define PART_OFF (640 * 1024)  // ws: 31 chunks (620 KB) + pad, then partials
#define CHUNK_BYTES 20480      // 20 KB of packed W-fragments per input channel i

typedef __attribute__((ext_vector_type(8))) _Float16 f16x8;
typedef __attribute__((ext_vector_type(4))) float f32x4;

__device__ inline short f2h(float f) {            // prep kernel only (cold): RNE
    union { _Float16 h; short s; } cv;
    cv.h = (_Float16)f;
    return cv.s;
}

// ---------------- prep: pack generator weights into MFMA fragment chunks ------
// ws layout: for i in [0,31): 20 chunks of 1 KB (20 KB per i, 620 KB total):
//   pairs 0..7 : spline W, chunk = kc*2 + ot  (kc in [0,8), ot in {0,1})
//   pair 8 (chunks 16,17) : uw W;  pair 9 (chunks 18,19) : rw W   (FP16)
// Chunk lane l, elem j = W[o = ot*16+(l&15)][c = (l>>4)*8+j]; c==31 carries the
// bias (x~[31]=1), o==31 rows are zero. Same data works as A or B operand
// (verified by R4-lineage and R10 both passing).
__global__ __launch_bounds__(64) void kan_prep_kernel(
    const float* __restrict__ gw, const float* __restrict__ gb,
    unsigned short* __restrict__ ws)
{
    const int blk = blockIdx.x;          // 31*20 = 620
    const int i   = blk / 20;
    const int ch  = blk % 20;
    const int l   = threadIdx.x;
    const int col = l & 15;
    const int krow = l >> 4;
    const int o = (ch & 1) * 16 + col;

    int p;
    if (ch < 16)      p = (i * 31 + o) * 8 + (ch >> 1);
    else if (ch < 18) p = UW_OFF + i * 31 + o;
    else              p = RW_OFF + i * 31 + o;

    short v8[8];
#pragma unroll
    for (int j = 0; j < 8; ++j) {
        const int c = krow * 8 + j;
        float v = 0.f;
        if (o < OUT_C) v = (c < IN_C) ? gw[p * 31 + c] : gb[p];
        v8[j] = f2h(v);
    }
    *(f16x8*)&ws[(blk * 64 + l) * 8] = *(f16x8*)v8;
}

// Stage one 20 KB chunk into LDS via async DMA (512 threads: 1280 16B slots =
// 2 full passes + waves 0..3 take the tail).
__device__ __forceinline__ void stage_i(const unsigned char* wsrc,
                                        unsigned char* ldst, int t) {
#pragma unroll
    for (int k = 0; k < 2; ++k) {
        const int off = (k * 512 + t) * 16;
        __builtin_amdgcn_global_load_lds(
            (const __attribute__((address_space(1))) unsigned int*)(wsrc + off),
            (__attribute__((address_space(3))) unsigned int*)(ldst + off),
            16, 0, 0);
    }
    if (t < 256) {                       // wave-uniform (waves 0..3)
        const int off = (1024 + t) * 16;
        __builtin_amdgcn_global_load_lds(
            (const __attribute__((address_space(1))) unsigned int*)(wsrc + off),
            (__attribute__((address_space(3))) unsigned int*)(ldst + off),
            16, 0, 0);
    }
}

// ---- operand-swapped i-body: W = A (from LDS), x~ = B (loop-invariant reg) ---
// Every MFMA input is a ds_read result or a stable register -- NO VALU->MFMA
// dependency (the chain that convoyed rounds 4-18). T/UW are zero-C transients
// folded immediately on the VALU using lane-local bas/sil (C-layout col = px).
__device__ __forceinline__ void body_swap(
    int i, const unsigned char* wb, const float* __restrict__ x, int pr0,
    f16x8 ax, f32x4 Y[2], int l)
{
    const float xv = x[i * NPIX + pr0];

    // basis (uniform cardinal cubic) + silu, f32, for this lane's pixel (l&15)
    float bas[8];
    const float tb = (xv + 2.2f) * 2.5f;
    const float jf = floorf(tb);
    const float u  = tb - jf;
    const int  jj  = (int)jf;
    const float u2 = u * u, u3 = u2 * u;
    const float b0v = u3 * (1.f / 6.f);
    const float b1v = (-3.f * u3 + 3.f * u2 + 3.f * u + 1.f) * (1.f / 6.f);
    const float b2v = (3.f * u3 - 6.f * u2 + 4.f) * (1.f / 6.f);
    const float omu = 1.f - u;
    const float b3v = omu * omu * omu * (1.f / 6.f);
#pragma unroll
    for (int m = 0; m < 8; ++m) {
        const int d = jj - m;
        bas[m] = (d == 0) ? b0v : (d == 1) ? b1v : (d == 2) ? b2v
               : (d == 3) ? b3v : 0.f;
    }
    const float sil = xv / (1.f + __expf(-xv));

    const f32x4 z = (f32x4){0.f, 0.f, 0.f, 0.f};
    f32x4 SP0 = z, SP1 = z;

    // spline: 16 independent zero-C MFMAs (pure ds_read -> MFMA stream);
    // fold T into SP with lane-local bas[p] (col = px = l&15).
#pragma unroll
    for (int p = 0; p < 8; ++p) {
        const f16x8 a0 = *(const f16x8*)(wb + ((p * 2 + 0) * 64 + l) * 16);
        const f16x8 a1 = *(const f16x8*)(wb + ((p * 2 + 1) * 64 + l) * 16);
        const f32x4 T0 = __builtin_amdgcn_mfma_f32_16x16x32_f16(a0, ax, z, 0, 0, 0);
        const f32x4 T1 = __builtin_amdgcn_mfma_f32_16x16x32_f16(a1, ax, z, 0, 0, 0);
#pragma unroll
        for (int r = 0; r < 4; ++r) {
            SP0[r] = fmaf(bas[p], T0[r], SP0[r]);
            SP1[r] = fmaf(bas[p], T1[r], SP1[r]);
        }
    }
    // uw + rw (zero-C transients), fold into Y: Y += UW*SP + sil*R
    {
        const f16x8 u0 = *(const f16x8*)(wb + (16 * 64 + l) * 16);
        const f16x8 u1 = *(const f16x8*)(wb + (17 * 64 + l) * 16);
        const f16x8 r0 = *(const f16x8*)(wb + (18 * 64 + l) * 16);
        const f16x8 r1 = *(const f16x8*)(wb + (19 * 64 + l) * 16);
        const f32x4 UW0 = __builtin_amdgcn_mfma_f32_16x16x32_f16(u0, ax, z, 0, 0, 0);
        const f32x4 UW1 = __builtin_amdgcn_mfma_f32_16x16x32_f16(u1, ax, z, 0, 0, 0);
        const f32x4 R0  = __builtin_amdgcn_mfma_f32_16x16x32_f16(r0, ax, z, 0, 0, 0);
        const f32x4 R1  = __builtin_amdgcn_mfma_f32_16x16x32_f16(r1, ax, z, 0, 0, 0);
#pragma unroll
        for (int r = 0; r < 4; ++r) {
            Y[0][r] = fmaf(UW0[r], SP0[r], fmaf(sil, R0[r], Y[0][r]));
            Y[1][r] = fmaf(UW1[r], SP1[r], fmaf(sil, R1[r], Y[1][r]));
        }
    }
}

// ---------------- main: pure-stream MFMA, 16 px/wave, 40 KB LDS ---------------
// Block = 512 thr = 8 waves x 16 px = 128 px. i-group (<=4) in pair-passes over
// a 2x20KB buffer pair. C-layout after swap: row = o, col = px -> lane's bas
// and sil are its own pixel's (l&15). Grid = (128 ptiles, 8 igroups) = 1024
// blocks. y=0 -> out, y>0 -> partials; combine sums.
__global__ __launch_bounds__(512) void kan_mfma15_kernel(
    const float* __restrict__ x,               // (31, 16384)
    const unsigned char* __restrict__ wsw,     // packed W fragments (bytes)
    float* __restrict__ parts,                 // (nsplit-1) x (31,16384)
    float* __restrict__ out,                   // (31, 16384)
    int nsplit)
{
    const int t = threadIdx.x;
    const int l = t & 63;
    const int w = t >> 6;                      // 0..7
    const int pix0 = blockIdx.x * 128;
    const int csize = (IN_C + nsplit - 1) / nsplit;   // 4 at nsplit=8
    const int ibase = blockIdx.y * csize;
    const int iend = min(ibase + csize, IN_C);

    __shared__ __align__(16) unsigned char bufs[2][CHUNK_BYTES]; // 40 KB

    const int pr0 = pix0 + w * 16 + (l & 15);  // this lane's pixel row

    // prologue: stage first pair (async; in flight during ax setup)
    stage_i(wsw + (size_t)ibase * CHUNK_BYTES, bufs[0], t);
    if (ibase + 1 < iend)
        stage_i(wsw + (size_t)(ibase + 1) * CHUNK_BYTES, bufs[1], t);

    // x~ B-fragment (f16, once per block): lane holds col px = l&15,
    // k-slots c = (l>>4)*8 + j.
    f16x8 ax;
    {
        const int cb = (l >> 4) * 8;
#pragma unroll
        for (int j = 0; j < 8; ++j) {
            const int c = cb + j;
            const float v = (c < IN_C) ? x[c * NPIX + pr0] : 1.0f;  // x~[31]=1
            ax[j] = (_Float16)v;
        }
    }

    f32x4 Y[2];
    Y[0] = (f32x4){0.f, 0.f, 0.f, 0.f};
    Y[1] = (f32x4){0.f, 0.f, 0.f, 0.f};

    __syncthreads();   // pair-0 data ready (drains vmcnt)

#pragma unroll 1
    for (int i0 = ibase; i0 < iend; i0 += 2) {
        if (i0 > ibase) {                      // restage this pair
            stage_i(wsw + (size_t)i0 * CHUNK_BYTES, bufs[0], t);
            if (i0 + 1 < iend)
                stage_i(wsw + (size_t)(i0 + 1) * CHUNK_BYTES, bufs[1], t);
            __syncthreads();                   // data ready
        }
        body_swap(i0, bufs[0], x, pr0, ax, Y, l);
        if (i0 + 1 < iend)
            body_swap(i0 + 1, bufs[1], x, pr0, ax, Y, l);
        __syncthreads();                       // readers done (or pre-gather)
    }

    // ---- gather Y into bufs (free now) for coalesced store ----
    // Swapped C layout: row = o = (l>>4)*4 + r (+16 for nt=1), col = px = l&15.
    float* yb = (float*)bufs;   // 128*33 floats = 16.9 KB <= 40 KB
#pragma unroll
    for (int nt = 0; nt < 2; ++nt)
#pragma unroll
        for (int r = 0; r < 4; ++r) {
            const int o = nt * 16 + (l >> 4) * 4 + r;
            const int p = w * 16 + (l & 15);
            if (o < OUT_C) yb[p * 33 + o] = Y[nt][r];
        }
    __syncthreads();

    float* dst = (blockIdx.y == 0) ? out
               : (parts + (size_t)(blockIdx.y - 1) * OUT_C * NPIX);
    for (int idx = t; idx < 128 * OUT_C; idx += 512) {
        const int n = idx & 127, o = idx >> 7;
        dst[o * NPIX + pix0 + n] = yb[n * 33 + o];
    }
}

// ---------------- combine: out += sum of npart partials (vectorized) ----------
__global__ __launch_bounds__(256) void kan_combine_kernel(
    float* __restrict__ out, const float* __restrict__ parts, int npart)
{
    const int e = blockIdx.x * 256 + threadIdx.x;   // float4 index
    const int nv = (OUT_C * NPIX) / 4;
    if (e < nv) {
        f32x4 a = ((const f32x4*)out)[e];
        for (int j = 0; j < npart; ++j)
            a += ((const f32x4*)parts)[e + (size_t)j * nv];
        ((f32x4*)out)[e] = a;
    }
}

extern "C" void kernel_launch(void* const* d_in, const int* in_sizes, int n_in,
                              void* d_out, int out_size, void* d_ws, size_t ws_size,
                              hipStream_t stream) {
    const float* x  = (const float*)d_in[0];
    const float* gw = (const float*)d_in[1];
    const float* gb = (const float*)d_in[2];
    float* out = (float*)d_out;
    unsigned short* ws = (unsigned short*)d_ws;
    float* parts = (float*)((char*)d_ws + PART_OFF);

    // 8-way i-split: 7 f32 partials (14.3 MB). Deterministic fallback.
    const size_t part_bytes = (size_t)OUT_C * NPIX * 4;
    int nsplit = 8;
    if (ws_size < PART_OFF + 7 * part_bytes) nsplit = 4;
    if (ws_size < PART_OFF + 3 * part_bytes) nsplit = 2;

    hipLaunchKernelGGL(kan_prep_kernel, dim3(620), dim3(64), 0, stream, gw, gb, ws);
    hipLaunchKernelGGL(kan_mfma15_kernel, dim3(NPIX / 128, nsplit), dim3(512), 0, stream,
                       x, (const unsigned char*)d_ws, parts, out, nsplit);
    const int nv = (OUT_C * NPIX) / 4;                 // 126976
    hipLaunchKernelGGL(kan_combine_kernel, dim3((nv + 255) / 256), dim3(256), 0, stream,
                       out, parts, nsplit - 1);
}